// Round 16
// baseline (67.475 us; speedup 1.0000x reference)
//
#include <hip/hip_runtime.h>

// DispCorrLayer: out[b,d,h,w] = (1/C) * sum_c in1[b,c,h,w] * in2[b,c,h,w-(D-d)]
// (zero when w + d < D). B=4 C=32 H=256 W=512 D=128, fp32.
//
// R16 = R15 (banded-GEMM MFMA + block-shared bf16 band buffer + 512B-
// contiguous nt stores) with staging slimmed:
//  - s1t REMOVED: in1 elements feed exactly one tile's A-fragment, so the
//    LDS round-trip was pure overhead. A-frags are loaded global->reg
//    (64B-coalesced per 16-lane group), scaled+packed in-reg, for all 4
//    tiles up front (loads overlap the s2t pack).
//  - WHALF 256->512 (full row per block): in2 halo overhead 1.5x -> 1.25x,
//    1024 blocks. 4 MFMA/store rounds per block.
//  - LDS 40KB (s2t) + 34KB (obs) = 74KB -> 2 blocks/CU, 4 waves/SIMD.

#define BB 4
#define CC 32
#define HH 256
#define WW 512
#define DD 128
#define HW (HH * WW)

#define NT 512               // 8 waves
#define S2N 640              // staged in2 cols: w' in [-128, 512)
#define OBW 136              // obs row stride in shorts (word bank = 68d+l)

typedef __attribute__((ext_vector_type(8))) short bf16x8;
typedef __attribute__((ext_vector_type(4))) float f32x4;
typedef __attribute__((ext_vector_type(2))) float f32x2;

__device__ __forceinline__ unsigned int pk2(float lo, float hi) {
    // RNE bf16 pair pack
    union { float f; unsigned int i; } x, y; x.f = lo; y.f = hi;
    unsigned int xi = x.i + 0x7fffu + ((x.i >> 16) & 1u);
    unsigned int yi = y.i + 0x7fffu + ((y.i >> 16) & 1u);
    return (xi >> 16) | (yi & 0xffff0000u);
}
__device__ __forceinline__ unsigned short pk1(float v) {
    union { float f; unsigned int i; } x; x.f = v;
    return (unsigned short)((x.i + 0x7fffu + ((x.i >> 16) & 1u)) >> 16);
}

// word index of the 16B chunk holding row `row`, k-chunk `kc` (8 bf16).
__device__ __forceinline__ int cidx(int row, int kc) {
    return (row * 4 + (kc ^ ((row >> 1) & 3))) * 4;
}

__global__ __launch_bounds__(NT, 2)
void disp_corr_kernel(const float* __restrict__ in1,
                      const float* __restrict__ in2,
                      float* __restrict__ out) {
    __shared__ __align__(16) unsigned int s2t[S2N * 16];      // 40 KB
    __shared__ __align__(16) unsigned short obs[DD * OBW];    // 34 KB bf16

    const int t = threadIdx.x;

    // XCD swizzle (bijective, 1024 = 8*128)
    const int xcd = blockIdx.x & 7, slot = blockIdx.x >> 3;
    const int work = (xcd << 7) + slot;
    const int h  = work & (HH - 1);
    const int b  = work >> 8;

    const float* p1 = in1 + (size_t)b * CC * HW + (size_t)h * WW;
    const float* p2 = in2 + (size_t)b * CC * HW + (size_t)h * WW;
    const float sc = 1.0f / (float)CC;

    const int lane = t & 63;
    const int wv   = t >> 6;
    const int cl   = lane & 15;       // fragment col (w' within tile)
    const int rg   = lane >> 4;       // fragment row group / k-chunk

    // ---- A-fragments for this wave's 4 tiles: global -> reg, x sc, pack ----
    // tile (ro): i = ro*8 + wv, w = i*16 + cl; lane reads c = rg*8 + ci.
    uint4 afr[4];
    {
        const int w0 = wv * 16 + cl;
        #pragma unroll
        for (int ro = 0; ro < 4; ++ro) {
            float f[8];
            #pragma unroll
            for (int ci = 0; ci < 8; ++ci)
                f[ci] = p1[(size_t)(rg * 8 + ci) * HW + ro * 128 + w0] * sc;
            afr[ro] = make_uint4(pk2(f[0], f[1]), pk2(f[2], f[3]),
                                 pk2(f[4], f[5]), pk2(f[6], f[7]));
        }
    }

    // ---- stage in2^T halo tile: 640 quad-units (kc, wg) ----
    #pragma unroll
    for (int k = 0; k < 2; ++k) {
        const int u = t + k * NT;
        if (u < 640) {
            const int kc = u & 3;
            const int wg = u >> 2;             // col group of 4, [0,160)
            const int wp = wg * 4 - DD;        // global w' (multiple of 4)
            float l[8][4];
            if (wp >= 0) {
                #pragma unroll
                for (int ci = 0; ci < 8; ++ci)
                    *(float4*)l[ci] =
                        *(const float4*)(p2 + (size_t)(kc * 8 + ci) * HW + wp);
            } else {
                #pragma unroll
                for (int ci = 0; ci < 8; ++ci)
                    #pragma unroll
                    for (int rr = 0; rr < 4; ++rr) l[ci][rr] = 0.f;
            }
            #pragma unroll
            for (int rr = 0; rr < 4; ++rr) {
                const int row = wg * 4 + rr;
                const uint4 uu = make_uint4(pk2(l[0][rr], l[1][rr]),
                                            pk2(l[2][rr], l[3][rr]),
                                            pk2(l[4][rr], l[5][rr]),
                                            pk2(l[6][rr], l[7][rr]));
                *(uint4*)&s2t[cidx(row, kc)] = uu;
            }
        }
    }
    __syncthreads();

    // ---- 4 rounds x {1 tile/wave MFMA + bf16 scatter, barrier, stream} ----
    const size_t obase = (size_t)b * DD * HW + (size_t)h * WW;

    #pragma unroll
    for (int ro = 0; ro < 4; ++ro) {
        const int i = ro * 8 + wv;                 // this wave's w-tile
        union { uint4 u; bf16x8 v; } a;
        a.u = afr[ro];
        #pragma unroll
        for (int mm = 0; mm <= 8; ++mm) {
            union { uint4 u; bf16x8 v; } bq;
            bq.u = *(const uint4*)&s2t[cidx((i + mm) * 16 + cl, rg)];
            f32x4 acc = {0.f, 0.f, 0.f, 0.f};
            acc = __builtin_amdgcn_mfma_f32_16x16x32_bf16(a.v, bq.v, acc, 0, 0, 0);
            // element (reg q): w-row r = 4rg+q, w'-col cl, d = 16mm + cl - r
            #pragma unroll
            for (int q = 0; q < 4; ++q) {
                const int r = rg * 4 + q;
                const int d = mm * 16 + cl - r;
                const bool ok = (mm == 0) ? (cl >= r)
                              : (mm == 8) ? (cl < r) : true;
                if (ok) obs[d * OBW + wv * 16 + r] = pk1(acc[q]);
            }
        }
        __syncthreads();
        // store phase: wave wv streams d-planes [16wv, 16wv+16);
        // one instr = 128 consecutive w = 512B contiguous (8 full lines).
        const float* op0 = out + obase + 128 * ro;
        #pragma unroll
        for (int p = 0; p < 16; ++p) {
            const int d = wv * 16 + p;
            const unsigned int u = *(const unsigned int*)&obs[d * OBW + 2 * lane];
            union { unsigned int i; float f; } lo, hi;
            lo.i = u << 16;
            hi.i = u & 0xffff0000u;
            f32x2 v = {lo.f, hi.f};
            __builtin_nontemporal_store(
                v, (f32x2*)(op0 + (size_t)d * HW + 2 * lane));
        }
        __syncthreads();
    }
}

extern "C" void kernel_launch(void* const* d_in, const int* in_sizes, int n_in,
                              void* d_out, int out_size, void* d_ws, size_t ws_size,
                              hipStream_t stream) {
    const float* in1 = (const float*)d_in[0];
    const float* in2 = (const float*)d_in[1];
    float* out = (float*)d_out;
    const int nblocks = BB * HH;                 // 1024
    disp_corr_kernel<<<nblocks, NT, 0, stream>>>(in1, in2, out);
}

// Round 17
// 66.556 us; speedup vs baseline: 1.0138x; 1.0138x over previous
//
#include <hip/hip_runtime.h>

// DispCorrLayer: out[b,d,h,w] = (1/C) * sum_c in1[b,c,h,w] * in2[b,c,h,w-(D-d)]
// (zero when w + d < D). B=4 C=32 H=256 W=512 D=128, fp32.
//
// R17 = R15 verbatim (measured best: 66.5 us). R16's staging trim was
// neutral-to-negative, so this locks the best-known configuration:
//  - banded-GEMM MFMA formulation: per (b,h,w-half), G = in1^T x in2 band
//    via mfma_f32_16x16x32_bf16 (bf16 LDS operand tiles, k-chunk XOR
//    swizzle, 1/32 scale folded into in1 staging).
//  - BLOCK-SHARED bf16 band buffer obs[128][136]: per round (8 tiles),
//    each wave computes one 16x16 tile (9 MFMAs, full 128-d band) and
//    scatters bf16; barrier; each wave streams 16 d-planes as 512B-
//    CONTIGUOUS dwordx2 nt stores (8 full 64B lines per instr). The write-
//    contiguity fix was the decisive lever (87 -> 66.5 us).
//  - LDS 74 KB -> 2 blocks/CU (4 waves/SIMD); 2048 blocks, XCD-swizzled.
// Sustained mixed-stream BW: ~5.15 TB/s (~82% of 6.3 TB/s achievable) --
// considered the practical roofline for this op's mandatory 342 MB traffic.

#define BB 4
#define CC 32
#define HH 256
#define WW 512
#define DD 128
#define HW (HH * WW)

#define NT 512               // 8 waves
#define WHALF 256            // w span per block
#define S2N 384              // staged in2 cols: w' in [wb-128, wb+256)
#define OBW 136              // obs row stride in shorts (word bank = 68d+l)

typedef __attribute__((ext_vector_type(8))) short bf16x8;
typedef __attribute__((ext_vector_type(4))) float f32x4;
typedef __attribute__((ext_vector_type(2))) float f32x2;

__device__ __forceinline__ unsigned int pk2(float lo, float hi) {
    // RNE bf16 pair pack
    union { float f; unsigned int i; } x, y; x.f = lo; y.f = hi;
    unsigned int xi = x.i + 0x7fffu + ((x.i >> 16) & 1u);
    unsigned int yi = y.i + 0x7fffu + ((y.i >> 16) & 1u);
    return (xi >> 16) | (yi & 0xffff0000u);
}
__device__ __forceinline__ unsigned short pk1(float v) {
    union { float f; unsigned int i; } x; x.f = v;
    return (unsigned short)((x.i + 0x7fffu + ((x.i >> 16) & 1u)) >> 16);
}

// word index of the 16B chunk holding row `row`, k-chunk `kc` (8 bf16).
__device__ __forceinline__ int cidx(int row, int kc) {
    return (row * 4 + (kc ^ ((row >> 1) & 3))) * 4;
}

__global__ __launch_bounds__(NT, 2)
void disp_corr_kernel(const float* __restrict__ in1,
                      const float* __restrict__ in2,
                      float* __restrict__ out) {
    __shared__ __align__(16) unsigned int s1t[WHALF * 16];    // 16 KB
    __shared__ __align__(16) unsigned int s2t[S2N * 16];      // 24 KB
    __shared__ __align__(16) unsigned short obs[DD * OBW];    // 34 KB bf16

    const int t = threadIdx.x;

    // XCD swizzle (bijective, 2048 = 8*256)
    const int xcd = blockIdx.x & 7, slot = blockIdx.x >> 3;
    const int work = (xcd << 8) + slot;
    const int wh = work & 1;
    const int h  = (work >> 1) & (HH - 1);
    const int b  = work >> 9;
    const int wb = wh * WHALF;

    const float* p1 = in1 + (size_t)b * CC * HW + (size_t)h * WW + wb;
    const float* p2 = in2 + (size_t)b * CC * HW + (size_t)h * WW;
    const float sc = 1.0f / (float)CC;

    // ---- staging pass 1: 512 units; unit = (dst, kc, wgroup of 4 w) ----
    {
        const bool one = (t < 256);
        const int u  = one ? t : t - 256;
        const int kc = u >> 6;                 // wave-uniform
        const int wg = u & 63;
        float l[8][4];
        if (one) {
            #pragma unroll
            for (int ci = 0; ci < 8; ++ci)
                *(float4*)l[ci] =
                    *(const float4*)(p1 + (size_t)(kc * 8 + ci) * HW + wg * 4);
            #pragma unroll
            for (int ci = 0; ci < 8; ++ci)
                #pragma unroll
                for (int rr = 0; rr < 4; ++rr) l[ci][rr] *= sc;
        } else {
            const int wp = wb + wg * 4 - DD;   // multiple of 4
            if (wp >= 0) {
                #pragma unroll
                for (int ci = 0; ci < 8; ++ci)
                    *(float4*)l[ci] =
                        *(const float4*)(p2 + (size_t)(kc * 8 + ci) * HW + wp);
            } else {
                #pragma unroll
                for (int ci = 0; ci < 8; ++ci)
                    #pragma unroll
                    for (int rr = 0; rr < 4; ++rr) l[ci][rr] = 0.f;
            }
        }
        #pragma unroll
        for (int rr = 0; rr < 4; ++rr) {
            const int row = wg * 4 + rr;
            const uint4 uu = make_uint4(pk2(l[0][rr], l[1][rr]),
                                        pk2(l[2][rr], l[3][rr]),
                                        pk2(l[4][rr], l[5][rr]),
                                        pk2(l[6][rr], l[7][rr]));
            unsigned int* dst = one ? &s1t[cidx(row, kc)] : &s2t[cidx(row, kc)];
            *(uint4*)dst = uu;
        }
    }
    // ---- staging pass 2: s2 cols 256..383 (128 units, t<128) ----
    if (t < 128) {
        const int kc = t >> 5;
        const int wg = 64 + (t & 31);
        const int wp = wb + wg * 4 - DD;       // >= 128, always valid
        float l[8][4];
        #pragma unroll
        for (int ci = 0; ci < 8; ++ci)
            *(float4*)l[ci] =
                *(const float4*)(p2 + (size_t)(kc * 8 + ci) * HW + wp);
        #pragma unroll
        for (int rr = 0; rr < 4; ++rr) {
            const int row = wg * 4 + rr;
            const uint4 uu = make_uint4(pk2(l[0][rr], l[1][rr]),
                                        pk2(l[2][rr], l[3][rr]),
                                        pk2(l[4][rr], l[5][rr]),
                                        pk2(l[6][rr], l[7][rr]));
            *(uint4*)&s2t[cidx(row, kc)] = uu;
        }
    }
    __syncthreads();

    // ---- 2 rounds x {1 tile/wave MFMA + bf16 scatter, barrier, stream} ----
    const int lane = t & 63;
    const int wv   = t >> 6;
    const int cl   = lane & 15;       // fragment col (w' within tile)
    const int rg   = lane >> 4;       // fragment row group (w)
    const size_t obase = (size_t)b * DD * HW + (size_t)h * WW + wb;

    #pragma unroll
    for (int ro = 0; ro < 2; ++ro) {
        const int i = ro * 8 + wv;                 // this wave's w-tile
        union { uint4 u; bf16x8 v; } a;
        a.u = *(const uint4*)&s1t[cidx(i * 16 + cl, rg)];
        #pragma unroll
        for (int mm = 0; mm <= 8; ++mm) {
            union { uint4 u; bf16x8 v; } bq;
            bq.u = *(const uint4*)&s2t[cidx((i + mm) * 16 + cl, rg)];
            f32x4 acc = {0.f, 0.f, 0.f, 0.f};
            acc = __builtin_amdgcn_mfma_f32_16x16x32_bf16(a.v, bq.v, acc, 0, 0, 0);
            // element (reg q): w-row r = 4rg+q, w'-col cl, d = 16mm + cl - r
            #pragma unroll
            for (int q = 0; q < 4; ++q) {
                const int r = rg * 4 + q;
                const int d = mm * 16 + cl - r;
                const bool ok = (mm == 0) ? (cl >= r)
                              : (mm == 8) ? (cl < r) : true;
                if (ok) obs[d * OBW + wv * 16 + r] = pk1(acc[q]);
            }
        }
        __syncthreads();
        // store phase: wave wv streams d-planes [16wv, 16wv+16);
        // one instr = 128 consecutive w = 512B contiguous (8 full lines).
        const float* op0 = out + obase + 128 * ro;
        #pragma unroll
        for (int p = 0; p < 16; ++p) {
            const int d = wv * 16 + p;
            const unsigned int u = *(const unsigned int*)&obs[d * OBW + 2 * lane];
            union { unsigned int i; float f; } lo, hi;
            lo.i = u << 16;
            hi.i = u & 0xffff0000u;
            f32x2 v = {lo.f, hi.f};
            __builtin_nontemporal_store(
                v, (f32x2*)(op0 + (size_t)d * HW + 2 * lane));
        }
        __syncthreads();
    }
}

extern "C" void kernel_launch(void* const* d_in, const int* in_sizes, int n_in,
                              void* d_out, int out_size, void* d_ws, size_t ws_size,
                              hipStream_t stream) {
    const float* in1 = (const float*)d_in[0];
    const float* in2 = (const float*)d_in[1];
    float* out = (float*)d_out;
    const int nblocks = BB * HH * 2;             // 2048
    disp_corr_kernel<<<nblocks, NT, 0, stream>>>(in1, in2, out);
}